// Round 11
// baseline (42.356 us; speedup 1.0000x reference)
//
#include <hip/hip_runtime.h>

// DifferentiableCIndexLoss:
//   mask[i,j] = (t[i] < t[j]) && (e[i]==1)
//   loss = sum sigmoid((r[j]-r[i])/SIGMA) * mask ;  count = sum mask
//   out  = loss / (count + 1e-6)
//
// R11 = R10 (best, 42.1us) + two targeted cuts:
//  (a) paired-rcp inner loop: 1/u + 1/v = (m0*v + m1*u) * rcp(u*v) -- one
//      quarter-rate rcp per TWO pairs (was one per pair; rcp = 8cyc/wave is
//      the largest single term). p = fminf(u*v, 3e38) guards overflow; pad
//      rows use FINITE E=1 (t=3 -> mask false -> excluded from num & count),
//      so a padded partner cannot poison the shared product.
//  (b) k_compact cursor: ONE device atomicAdd per block (was per wave) --
//      same-address device atomics serialize ~12ns each (R7->R8 lesson).
// Structure unchanged: pre-transformed sI=(2^s,t) compacted rows / sJ=(2^-s,t)
// cols, JTILE=64 LDS wave-uniform broadcast, RPT=4, plain partial stores,
// tiny double-precision finalize. No device-scope fences/spins.
//   s = r*log2e/sigma clamped to +-60: a=2^{si-sj} in [2^-120,2^120].

#define BLOCK 256
#define RPT 4                        // rows per thread
#define ROWS_PER_TILE (BLOCK * RPT)  // 1024
#define JTILE 64                     // cols per tile
#define NCOLGRP 256                  // 16384/64
#define GRID_MAIN 2048

__device__ __forceinline__ float fast_exp2(float x) { return __builtin_amdgcn_exp2f(x); }
__device__ __forceinline__ float fast_rcp(float x)  { return __builtin_amdgcn_rcpf(x); }
__device__ __forceinline__ float clamp60(float x)   { return fminf(fmaxf(x, -60.0f), 60.0f); }

// ---- 1) transform cols + compact active rows (block-aggregated cursor) ------
__global__ __launch_bounds__(BLOCK) void k_compact(
    const float* __restrict__ r, const float* __restrict__ t,
    const int* __restrict__ ev, int B, float kscale,
    int* __restrict__ cursor,          // zeroed by memset; final value = nactive
    float2* __restrict__ sI, float2* __restrict__ sJ) {
    const int tid = threadIdx.x;
    int g = blockIdx.x * BLOCK + tid;
    if (g >= B) return;
    float tv = t[g];
    float s  = clamp60(r[g] * kscale);
    sJ[g] = make_float2(fast_exp2(-s), tv);        // F_j = 2^{-s_j}
    bool pred = (ev[g] == 1);
    unsigned long long bal = __ballot(pred);
    int lane = tid & 63, wid = tid >> 6;
    int before = __popcll(bal & ((1ull << lane) - 1ull));
    int wcnt = __popcll(bal);
    __shared__ int wbase[BLOCK / 64];
    if (lane == 0) wbase[wid] = wcnt;
    __syncthreads();
    if (tid == 0) {
        int c0 = wbase[0], c1 = wbase[1], c2 = wbase[2], c3 = wbase[3];
        int b0 = atomicAdd(cursor, (c0 + c1) + (c2 + c3));  // ONE atomic/block
        wbase[0] = b0; wbase[1] = b0 + c0; wbase[2] = b0 + c0 + c1;
        wbase[3] = b0 + c0 + c1 + c2;
    }
    __syncthreads();
    if (pred) sI[wbase[wid] + before] = make_float2(fast_exp2(s), tv);
}

// ---- 2) main: all-pairs over compacted rows, paired-rcp inner loop ----------
__global__ __launch_bounds__(BLOCK) void k_main(
    const float2* __restrict__ sI, const float2* __restrict__ sJ,
    const int* __restrict__ nactive_g,
    float* __restrict__ pL, unsigned int* __restrict__ pC) {

    const int tid = threadIdx.x;
    const int nactive = *nactive_g;
    const int nrc = (nactive + ROWS_PER_TILE - 1) / ROWS_PER_TILE;  // ~8
    const int ntiles = nrc * NCOLGRP;                                // ~2048

    __shared__ float2 tile[JTILE];

    float lsum = 0.0f;
    int   csum = 0;

    for (int tix = blockIdx.x; tix < ntiles; tix += gridDim.x) {
        int rc = tix >> 8;            // row chunk (ntiles = nrc*256)
        int cg = tix & (NCOLGRP - 1); // col group

        // 4 rows/thread, coalesced float2 loads, once per tile
        float E[RPT], T[RPT];
        int rbase = rc * ROWS_PER_TILE;
#pragma unroll
        for (int k = 0; k < RPT; ++k) {
            int rr = rbase + tid + (k << 8);
            if (rr < nactive) { float2 f = sI[rr]; E[k] = f.x; T[k] = f.y; }
            else              { E[k] = 1.0f; T[k] = 3.0f; }
            // pad: FINITE E (mask kills num & count); NOT inf (shared product!)
        }

        __syncthreads();              // protect tile[] from previous iteration
        if (tid < JTILE) tile[tid] = sJ[(cg << 6) + tid];
        __syncthreads();

        float l0 = 0.f, l1 = 0.f;
        int c = 0;
#pragma unroll 8
        for (int jj = 0; jj < JTILE; ++jj) {
            float2 q = tile[jj];      // wave-uniform LDS broadcast
            float F = q.x, tj = q.y;
            // pairs (0,1): one rcp for two sigmoids
            float u0 = __builtin_fmaf(E[0], F, 1.0f);
            float v0 = __builtin_fmaf(E[1], F, 1.0f);
            float p0 = fminf(u0 * v0, 3.0e38f);
            float rp0 = fast_rcp(p0);
            bool m0 = T[0] < tj, m1 = T[1] < tj;
            float num0 = (m0 ? v0 : 0.0f) + (m1 ? u0 : 0.0f);
            l0 = __builtin_fmaf(num0, rp0, l0);
            c += m0; c += m1;
            // pairs (2,3)
            float u1 = __builtin_fmaf(E[2], F, 1.0f);
            float v1 = __builtin_fmaf(E[3], F, 1.0f);
            float p1 = fminf(u1 * v1, 3.0e38f);
            float rp1 = fast_rcp(p1);
            bool m2 = T[2] < tj, m3 = T[3] < tj;
            float num1 = (m2 ? v1 : 0.0f) + (m3 ? u1 : 0.0f);
            l1 = __builtin_fmaf(num1, rp1, l1);
            c += m2; c += m3;
        }
        lsum += l0 + l1;
        csum += c;
    }

    // block reduce + plain partial stores
#pragma unroll
    for (int off = 32; off > 0; off >>= 1) {
        lsum += __shfl_down(lsum, off);
        csum += __shfl_down(csum, off);
    }
    __shared__ float lw[BLOCK / 64];
    __shared__ int   cw[BLOCK / 64];
    int wid = tid >> 6;
    if ((tid & 63) == 0) { lw[wid] = lsum; cw[wid] = csum; }
    __syncthreads();
    if (tid == 0) {
        pL[blockIdx.x] = (lw[0] + lw[1]) + (lw[2] + lw[3]);
        pC[blockIdx.x] = (unsigned)((cw[0] + cw[1]) + (cw[2] + cw[3]));
    }
}

// ---- 3) finalize -------------------------------------------------------------
__global__ __launch_bounds__(BLOCK) void k_finalize(
    const float* __restrict__ pL, const unsigned int* __restrict__ pC,
    int n, float* __restrict__ out) {
    double l = 0.0, c = 0.0;
    for (int i = threadIdx.x; i < n; i += BLOCK) {
        l += (double)pL[i];
        c += (double)pC[i];
    }
#pragma unroll
    for (int off = 32; off > 0; off >>= 1) {
        l += __shfl_down(l, off);
        c += __shfl_down(c, off);
    }
    __shared__ double lw[BLOCK / 64], cw[BLOCK / 64];
    int wid = threadIdx.x >> 6;
    if ((threadIdx.x & 63) == 0) { lw[wid] = l; cw[wid] = c; }
    __syncthreads();
    if (threadIdx.x == 0) {
        double L = (lw[0] + lw[1]) + (lw[2] + lw[3]);
        double C = (cw[0] + cw[1]) + (cw[2] + cw[3]);
        out[0] = (float)(L / (C + 1e-6));
    }
}

extern "C" void kernel_launch(void* const* d_in, const int* in_sizes, int n_in,
                              void* d_out, int out_size, void* d_ws, size_t ws_size,
                              hipStream_t stream) {
    const float* r  = (const float*)d_in[0];
    const float* t  = (const float*)d_in[1];
    const int*   ev = (const int*)d_in[2];
    float* out = (float*)d_out;
    const int B = in_sizes[0];   // 16384

    const float SIGMA = 0.1f;
    const float LOG2E = 1.4426950408889634f;
    const float kscale = LOG2E / SIGMA;

    char* ws = (char*)d_ws;
    int* cursor = (int*)ws;                        // [0,64): atomic cursor = nactive
    float2* sI  = (float2*)(ws + 4096);            // 128 KB (compacted rows: E, t)
    float2* sJ  = sI + B;                          // 128 KB (all cols: F, t)
    float*  pL  = (float*)(sJ + B);
    unsigned int* pC = (unsigned int*)(pL + GRID_MAIN);

    const int nblk = (B + BLOCK - 1) / BLOCK;      // 64

    hipMemsetAsync(ws, 0, 64, stream);
    k_compact<<<nblk, BLOCK, 0, stream>>>(r, t, ev, B, kscale, cursor, sI, sJ);
    k_main<<<GRID_MAIN, BLOCK, 0, stream>>>(sI, sJ, cursor, pL, pC);
    k_finalize<<<1, BLOCK, 0, stream>>>(pL, pC, GRID_MAIN, out);
}

// Round 12
// 40.856 us; speedup vs baseline: 1.0367x; 1.0367x over previous
//
#include <hip/hip_runtime.h>

// DifferentiableCIndexLoss:
//   mask[i,j] = (t[i] < t[j]) && (e[i]==1)
//   loss = sum sigmoid((r[j]-r[i])/SIGMA) * mask ;  count = sum mask
//   out  = loss / (count + 1e-6)
//
// R12 = R11 with ONE variable changed: tile/block geometry.
//   grid 1024 (was 2048), JTILE=128 (was 64)  =>  tiles = nrc*128 ~= 1024.
//   Same total pair work, but HALF the blocks: half the launch ramp, half the
//   row loads (rows reused across 128 cols instead of 64), half the
//   barriers/reduces/partial-stores. Diagnoses the persistent ~2x gap between
//   main's ~28us and its ~14us issue floor (R11's inner-loop cut was neutral
//   => not issue-bound; suspects are per-block overheads).
// Kept: pre-transformed sI=(2^s,t)/sJ=(2^-s,t), paired-rcp (one rcp per two
// pairs, clamped product, finite pad rows), LDS wave-uniform broadcast,
// plain partial stores + double finalize. No device-scope fences/spins.
//   s = r*log2e/sigma clamped to +-60: 2^{si-sj} in [2^-120,2^120].

#define BLOCK 256
#define RPT 4                        // rows per thread
#define ROWS_PER_TILE (BLOCK * RPT)  // 1024
#define JTILE 128                    // cols per tile
#define NCOLGRP 128                  // 16384/128
#define GRID_MAIN 1024

__device__ __forceinline__ float fast_exp2(float x) { return __builtin_amdgcn_exp2f(x); }
__device__ __forceinline__ float fast_rcp(float x)  { return __builtin_amdgcn_rcpf(x); }
__device__ __forceinline__ float clamp60(float x)   { return fminf(fmaxf(x, -60.0f), 60.0f); }

// ---- 1) transform cols + compact active rows (block-aggregated cursor) ------
__global__ __launch_bounds__(BLOCK) void k_compact(
    const float* __restrict__ r, const float* __restrict__ t,
    const int* __restrict__ ev, int B, float kscale,
    int* __restrict__ cursor,          // zeroed by memset; final value = nactive
    float2* __restrict__ sI, float2* __restrict__ sJ) {
    const int tid = threadIdx.x;
    int g = blockIdx.x * BLOCK + tid;
    if (g >= B) return;
    float tv = t[g];
    float s  = clamp60(r[g] * kscale);
    sJ[g] = make_float2(fast_exp2(-s), tv);        // F_j = 2^{-s_j}
    bool pred = (ev[g] == 1);
    unsigned long long bal = __ballot(pred);
    int lane = tid & 63, wid = tid >> 6;
    int before = __popcll(bal & ((1ull << lane) - 1ull));
    int wcnt = __popcll(bal);
    __shared__ int wbase[BLOCK / 64];
    if (lane == 0) wbase[wid] = wcnt;
    __syncthreads();
    if (tid == 0) {
        int c0 = wbase[0], c1 = wbase[1], c2 = wbase[2], c3 = wbase[3];
        int b0 = atomicAdd(cursor, (c0 + c1) + (c2 + c3));  // ONE atomic/block
        wbase[0] = b0; wbase[1] = b0 + c0; wbase[2] = b0 + c0 + c1;
        wbase[3] = b0 + c0 + c1 + c2;
    }
    __syncthreads();
    if (pred) sI[wbase[wid] + before] = make_float2(fast_exp2(s), tv);
}

// ---- 2) main: all-pairs over compacted rows, 1024x128 tiles -----------------
__global__ __launch_bounds__(BLOCK) void k_main(
    const float2* __restrict__ sI, const float2* __restrict__ sJ,
    const int* __restrict__ nactive_g,
    float* __restrict__ pL, unsigned int* __restrict__ pC) {

    const int tid = threadIdx.x;
    const int nactive = *nactive_g;
    const int nrc = (nactive + ROWS_PER_TILE - 1) / ROWS_PER_TILE;  // ~8
    const int ntiles = nrc * NCOLGRP;                                // ~1024

    __shared__ float2 tile[JTILE];

    float lsum = 0.0f;
    int   csum = 0;

    for (int tix = blockIdx.x; tix < ntiles; tix += gridDim.x) {
        int rc = tix >> 7;            // row chunk (ntiles = nrc*128)
        int cg = tix & (NCOLGRP - 1); // col group

        // 4 rows/thread, coalesced float2 loads, once per tile (128 cols reuse)
        float E[RPT], T[RPT];
        int rbase = rc * ROWS_PER_TILE;
#pragma unroll
        for (int k = 0; k < RPT; ++k) {
            int rr = rbase + tid + (k << 8);
            if (rr < nactive) { float2 f = sI[rr]; E[k] = f.x; T[k] = f.y; }
            else              { E[k] = 1.0f; T[k] = 3.0f; }
            // pad: FINITE E (mask kills num & count); NOT inf (shared product!)
        }

        __syncthreads();              // protect tile[] from previous iteration
        if (tid < JTILE) tile[tid] = sJ[(cg << 7) + tid];
        __syncthreads();

        float l0 = 0.f, l1 = 0.f;
        int c = 0;
#pragma unroll 8
        for (int jj = 0; jj < JTILE; ++jj) {
            float2 q = tile[jj];      // wave-uniform LDS broadcast
            float F = q.x, tj = q.y;
            // pairs (0,1): one rcp for two sigmoids
            float u0 = __builtin_fmaf(E[0], F, 1.0f);
            float v0 = __builtin_fmaf(E[1], F, 1.0f);
            float p0 = fminf(u0 * v0, 3.0e38f);
            float rp0 = fast_rcp(p0);
            bool m0 = T[0] < tj, m1 = T[1] < tj;
            float num0 = (m0 ? v0 : 0.0f) + (m1 ? u0 : 0.0f);
            l0 = __builtin_fmaf(num0, rp0, l0);
            c += m0; c += m1;
            // pairs (2,3)
            float u1 = __builtin_fmaf(E[2], F, 1.0f);
            float v1 = __builtin_fmaf(E[3], F, 1.0f);
            float p1 = fminf(u1 * v1, 3.0e38f);
            float rp1 = fast_rcp(p1);
            bool m2 = T[2] < tj, m3 = T[3] < tj;
            float num1 = (m2 ? v1 : 0.0f) + (m3 ? u1 : 0.0f);
            l1 = __builtin_fmaf(num1, rp1, l1);
            c += m2; c += m3;
        }
        lsum += l0 + l1;
        csum += c;
    }

    // block reduce + plain partial stores
#pragma unroll
    for (int off = 32; off > 0; off >>= 1) {
        lsum += __shfl_down(lsum, off);
        csum += __shfl_down(csum, off);
    }
    __shared__ float lw[BLOCK / 64];
    __shared__ int   cw[BLOCK / 64];
    int wid = tid >> 6;
    if ((tid & 63) == 0) { lw[wid] = lsum; cw[wid] = csum; }
    __syncthreads();
    if (tid == 0) {
        pL[blockIdx.x] = (lw[0] + lw[1]) + (lw[2] + lw[3]);
        pC[blockIdx.x] = (unsigned)((cw[0] + cw[1]) + (cw[2] + cw[3]));
    }
}

// ---- 3) finalize -------------------------------------------------------------
__global__ __launch_bounds__(BLOCK) void k_finalize(
    const float* __restrict__ pL, const unsigned int* __restrict__ pC,
    int n, float* __restrict__ out) {
    double l = 0.0, c = 0.0;
    for (int i = threadIdx.x; i < n; i += BLOCK) {
        l += (double)pL[i];
        c += (double)pC[i];
    }
#pragma unroll
    for (int off = 32; off > 0; off >>= 1) {
        l += __shfl_down(l, off);
        c += __shfl_down(c, off);
    }
    __shared__ double lw[BLOCK / 64], cw[BLOCK / 64];
    int wid = threadIdx.x >> 6;
    if ((threadIdx.x & 63) == 0) { lw[wid] = l; cw[wid] = c; }
    __syncthreads();
    if (threadIdx.x == 0) {
        double L = (lw[0] + lw[1]) + (lw[2] + lw[3]);
        double C = (cw[0] + cw[1]) + (cw[2] + cw[3]);
        out[0] = (float)(L / (C + 1e-6));
    }
}

extern "C" void kernel_launch(void* const* d_in, const int* in_sizes, int n_in,
                              void* d_out, int out_size, void* d_ws, size_t ws_size,
                              hipStream_t stream) {
    const float* r  = (const float*)d_in[0];
    const float* t  = (const float*)d_in[1];
    const int*   ev = (const int*)d_in[2];
    float* out = (float*)d_out;
    const int B = in_sizes[0];   // 16384

    const float SIGMA = 0.1f;
    const float LOG2E = 1.4426950408889634f;
    const float kscale = LOG2E / SIGMA;

    char* ws = (char*)d_ws;
    int* cursor = (int*)ws;                        // [0,64): atomic cursor = nactive
    float2* sI  = (float2*)(ws + 4096);            // 128 KB (compacted rows: E, t)
    float2* sJ  = sI + B;                          // 128 KB (all cols: F, t)
    float*  pL  = (float*)(sJ + B);
    unsigned int* pC = (unsigned int*)(pL + GRID_MAIN);

    const int nblk = (B + BLOCK - 1) / BLOCK;      // 64

    hipMemsetAsync(ws, 0, 64, stream);
    k_compact<<<nblk, BLOCK, 0, stream>>>(r, t, ev, B, kscale, cursor, sI, sJ);
    k_main<<<GRID_MAIN, BLOCK, 0, stream>>>(sI, sJ, cursor, pL, pC);
    k_finalize<<<1, BLOCK, 0, stream>>>(pL, pC, GRID_MAIN, out);
}